// Round 2
// baseline (575.709 us; speedup 1.0000x reference)
//
#include <hip/hip_runtime.h>
#include <hip/hip_bf16.h>
#include <math.h>

#define B_ROWS 16384
#define DIM    1024
#define CLS    1000
#define KC     15

typedef __attribute__((ext_vector_type(8))) short short8;
typedef __attribute__((ext_vector_type(4))) float f32x4;

__device__ __forceinline__ unsigned short bf16rtn(float x) {
    unsigned u = __float_as_uint(x);
    unsigned r = (u + 0x7FFFu + ((u >> 16) & 1u)) >> 16;
    return (unsigned short)r;
}

// ---------------- K1: centroid normalize -> bf16, [3][16][1024], row 15 zeroed ----------------
__global__ __launch_bounds__(256) void k1_centnorm(const float* c0, const float* c1, const float* c2,
                                                   unsigned short* cnorm) {
    int bx = blockIdx.x;            // 0..47
    int m = bx >> 4, k = bx & 15;
    int t = threadIdx.x;
    unsigned short* outp = cnorm + ((m * 16 + k) << 10);
    if (k == 15) {
        outp[t * 4 + 0] = 0; outp[t * 4 + 1] = 0; outp[t * 4 + 2] = 0; outp[t * 4 + 3] = 0;
        return;
    }
    const float* src = (m == 0 ? c0 : (m == 1 ? c1 : c2)) + (k << 10);
    float4 f = ((const float4*)src)[t];
    float s = f.x * f.x + f.y * f.y + f.z * f.z + f.w * f.w;
    for (int d = 1; d < 64; d <<= 1) s += __shfl_xor(s, d);
    __shared__ float r4[4];
    int w = t >> 6, lane = t & 63;
    if (lane == 0) r4[w] = s;
    __syncthreads();
    float tot = r4[0] + r4[1] + r4[2] + r4[3];
    float inv = 1.0f / fmaxf(sqrtf(tot), 1e-12f);
    outp[t * 4 + 0] = bf16rtn(f.x * inv);
    outp[t * 4 + 1] = bf16rtn(f.y * inv);
    outp[t * 4 + 2] = bf16rtn(f.z * inv);
    outp[t * 4 + 3] = bf16rtn(f.w * inv);
}

// ---------------- K2: sims via MFMA; one 16-row tile per wave ----------------
__global__ __launch_bounds__(256) void k2_sim(const float* f0, const float* f1, const float* f2,
                                              const unsigned short* cnorm, float* avg, int* assign) {
    int t = threadIdx.x;
    int lane = t & 63, w = t >> 6;
    int wg = blockIdx.x * 4 + w;        // 0..3071
    int m = wg >> 10;
    int tile = wg & 1023;
    int row_base = tile << 4;
    const float* fea = (m == 0 ? f0 : (m == 1 ? f1 : f2));

    int nrow = lane & 15;
    int k8 = (lane >> 4) << 3;
    const float* aptr = fea + (size_t)(row_base + nrow) * DIM + k8;
    const short8* bptr = (const short8*)(cnorm + ((m * 16 + nrow) << 10) + k8);

    f32x4 acc = {0.0f, 0.0f, 0.0f, 0.0f};
    float nacc = 0.0f;

#pragma unroll 8
    for (int s = 0; s < 32; ++s) {
        float4 a0 = *(const float4*)(aptr + s * 32);
        float4 a1 = *(const float4*)(aptr + s * 32 + 4);
        short8 bfr = bptr[s * 4];
        short8 afr;
        afr[0] = (short)bf16rtn(a0.x); afr[1] = (short)bf16rtn(a0.y);
        afr[2] = (short)bf16rtn(a0.z); afr[3] = (short)bf16rtn(a0.w);
        afr[4] = (short)bf16rtn(a1.x); afr[5] = (short)bf16rtn(a1.y);
        afr[6] = (short)bf16rtn(a1.z); afr[7] = (short)bf16rtn(a1.w);
        nacc = fmaf(a0.x, a0.x, nacc);
        nacc = fmaf(a0.y, a0.y, nacc);
        nacc = fmaf(a0.z, a0.z, nacc);
        nacc = fmaf(a0.w, a0.w, nacc);
        nacc = fmaf(a1.x, a1.x, nacc);
        nacc = fmaf(a1.y, a1.y, nacc);
        nacc = fmaf(a1.z, a1.z, nacc);
        nacc = fmaf(a1.w, a1.w, nacc);
        acc = __builtin_amdgcn_mfma_f32_16x16x32_bf16(afr, bfr, acc, 0, 0, 0);
    }

    float nsq = nacc;
    nsq += __shfl_xor(nsq, 16);
    nsq += __shfl_xor(nsq, 32);
    float inv = 1.0f / fmaxf(sqrtf(nsq), 1e-12f);

    int c = lane & 15;
    int quad = lane >> 4;
#pragma unroll
    for (int j = 0; j < 4; ++j) {
        int r = quad * 4 + j;
        float invr = __shfl(inv, r);
        float simv = acc[j] * invr;
        float sv = (c < 15) ? simv : 0.0f;
        float mv = (c < 15) ? simv : -INFINITY;
        int mi = c;
        for (int s = 1; s <= 8; s <<= 1) {
            sv += __shfl_xor(sv, s);
            float ov = __shfl_xor(mv, s);
            int oi = __shfl_xor(mi, s);
            bool take = (ov > mv) || (ov == mv && oi < mi);
            mv = take ? ov : mv;
            mi = take ? oi : mi;
        }
        if (c == 0) {
            int row = row_base + r;
            avg[m * B_ROWS + row] = sv * (1.0f / 15.0f);
            assign[m * B_ROWS + row] = mi;
        }
    }
}

// ---------------- K3: exact kth-smallest (rank 6554, 0-based) + attractive loss ----------------
__global__ __launch_bounds__(1024) void k3_select(const float* avg, float* attr_out) {
    int m = blockIdx.x;
    int t = threadIdx.x;
    const float* a = avg + m * B_ROWS;
    float av[16];
    unsigned kv[16];
#pragma unroll
    for (int i = 0; i < 16; ++i) {
        float x = a[i * 1024 + t];
        av[i] = x;
        unsigned u = __float_as_uint(x);
        kv[i] = (u & 0x80000000u) ? ~u : (u | 0x80000000u);
    }
    __shared__ unsigned sP, sR;
    __shared__ int ri[16];
    __shared__ float rf[16];
    if (t == 0) { sP = 0u; sR = 6554u; }
    __syncthreads();
    int w = t >> 6, lane = t & 63;
    for (int bit = 31; bit >= 0; --bit) {
        unsigned pref = sP;
        unsigned rr = sR;
        unsigned maskH = (bit == 31) ? 0u : (0xFFFFFFFFu << (bit + 1));
        int cnt = 0;
#pragma unroll
        for (int i = 0; i < 16; ++i) {
            bool match = (((kv[i] ^ pref) & maskH) == 0u);
            bool zero = (((kv[i] >> bit) & 1u) == 0u);
            cnt += (match && zero) ? 1 : 0;
        }
        for (int d = 1; d < 64; d <<= 1) cnt += __shfl_xor(cnt, d);
        if (lane == 0) ri[w] = cnt;
        __syncthreads();
        if (t == 0) {
            int c0 = 0;
            for (int i = 0; i < 16; ++i) c0 += ri[i];
            if ((int)rr >= c0) { sP = pref | (1u << bit); sR = rr - (unsigned)c0; }
        }
        __syncthreads();
    }
    unsigned key = sP;
    float thr = (key & 0x80000000u) ? __uint_as_float(key & 0x7FFFFFFFu)
                                    : __uint_as_float(~key);
    float s = 0.0f;
#pragma unroll
    for (int i = 0; i < 16; ++i) {
        float x = av[i];
        float wgt = 1.0f / (1.0f + __expf(-5.0f * (x - thr)));
        s += wgt * (1.0f - x);
    }
    for (int d = 1; d < 64; d <<= 1) s += __shfl_xor(s, d);
    if (lane == 0) rf[w] = s;
    __syncthreads();
    if (t == 0) {
        float tot = 0.0f;
        for (int i = 0; i < 16; ++i) tot += rf[i];
        attr_out[m] = tot / 16384.0f;
    }
}

// ---------------- K4: per-row sumexp + exact out copy ----------------
__global__ __launch_bounds__(256) void k4_softprep(const float* out_in, float* out_copy, float* inv_denom) {
    int w = threadIdx.x >> 6, lane = threadIdx.x & 63;
    int row = blockIdx.x * 4 + w;
    const float4* src = (const float4*)(out_in + (size_t)row * CLS);
    float4* dst = (float4*)(out_copy + (size_t)row * CLS);
    float s = 0.0f;
#pragma unroll
    for (int i = 0; i < 4; ++i) {
        int idx = i * 64 + lane;
        if (idx < 250) {
            float4 v = src[idx];
            dst[idx] = v;
            s += __expf(v.x) + __expf(v.y) + __expf(v.z) + __expf(v.w);
        }
    }
    for (int d = 1; d < 64; d <<= 1) s += __shfl_xor(s, d);
    if (lane == 0) inv_denom[row] = 1.0f / s;
}

// ---------------- K5: LDS-atomic segment accumulation (ds_add_f32, no register switch) ----------------
// red[3][KC][256] = 46080 B LDS -> 2 blocks/CU (wave-capacity-limited anyway).
// Per row-iteration: 1 global load + expf + 3 ds_add_f32. Lanes hit consecutive cl
// addresses -> conflict-free banks; cross-wave same-address collisions are just
// pipelined LDS instruction slots (fire-and-forget atomics).
__global__ __launch_bounds__(1024) void k5_seg(const float* out_in, const float* inv_denom,
                                               const int* assign, float* partials) {
    int t = threadIdx.x;
    int slot = t >> 8;          // 4 row slots
    int cl = t & 255;           // local column (<250 active)
    int q = blockIdx.y;         // column quarter
    bool active = (cl < 250);
    int colbase = q * 250 + cl;

    __shared__ float red[3 * KC * 256];
    for (int i = t; i < 3 * KC * 256; i += 1024) red[i] = 0.0f;
    __syncthreads();

    for (int row = blockIdx.x * 4 + slot; row < B_ROWS; row += 256) {
        int a0 = assign[row];
        int a1 = assign[B_ROWS + row];
        int a2 = assign[2 * B_ROWS + row];
        if (active) {
            float p = __expf(out_in[(size_t)row * CLS + colbase]) * inv_denom[row];
            atomicAdd(&red[a0 * 256 + cl], p);
            atomicAdd(&red[(KC + a1) * 256 + cl], p);
            atomicAdd(&red[(2 * KC + a2) * 256 + cl], p);
        }
    }
    __syncthreads();

    float* dst = partials + (size_t)(blockIdx.y * 64 + blockIdx.x) * (3 * KC * 250);
    for (int i = t; i < 3 * KC * 250; i += 1024) {
        dst[i] = red[(i / 250) * 256 + (i % 250)];
    }
}

// ---------------- K6a: fully-parallel reduce of partials over the 64 row-blocks ----------------
// sums[q][m][k][cl], ascending-b order (same rounding order as the old K6 inner loop).
__global__ __launch_bounds__(256) void k6a_reduce(const float* partials, float* sums) {
    int i = blockIdx.x * 256 + threadIdx.x;     // 0..44999
    if (i >= 4 * 3 * KC * 250) return;
    int q = i / (3 * KC * 250);
    int j = i - q * (3 * KC * 250);
    const float* p = partials + (size_t)q * 64 * (3 * KC * 250) + j;
    float s = 0.0f;
#pragma unroll 4
    for (int b = 0; b < 64; ++b)
        s += p[(size_t)b * (3 * KC * 250)];
    sums[i] = s;
}

// ---------------- K6b: per-(m,k) entropy from sums, gated on count>=3 ----------------
__global__ __launch_bounds__(256) void k6b_entropy(const int* assign, const float* sums,
                                                   float* ent_out) {
    int bx = blockIdx.x;        // 0..44
    int m = bx / KC, k = bx % KC;
    int t = threadIdx.x;
    int w = t >> 6, lane = t & 63;
    int cnt = 0;
    for (int e = t; e < B_ROWS; e += 256) cnt += (assign[m * B_ROWS + e] == k) ? 1 : 0;
    for (int d = 1; d < 64; d <<= 1) cnt += __shfl_xor(cnt, d);
    __shared__ int ri[4];
    __shared__ float rf[4];
    if (lane == 0) ri[w] = cnt;
    __syncthreads();
    int count = ri[0] + ri[1] + ri[2] + ri[3];
    float denom = fmaxf((float)count, 1.0f);
    float es = 0.0f;
    for (int c = t; c < CLS; c += 256) {
        int q = c / 250, cl = c % 250;
        float s = sums[q * (3 * KC * 250) + (m * KC + k) * 250 + cl];
        float mp = s / denom;
        es += mp * __logf(mp + 1e-8f);
    }
    for (int d = 1; d < 64; d <<= 1) es += __shfl_xor(es, d);
    if (lane == 0) rf[w] = es;
    __syncthreads();
    if (t == 0) {
        float ent = rf[0] + rf[1] + rf[2] + rf[3];
        ent_out[m * KC + k] = (count >= 3) ? ent : 0.0f;
    }
}

// ---------------- K7: final scalar ----------------
__global__ __launch_bounds__(64) void k7_final(const float* attr, const float* ent, float* out_loss) {
    int t = threadIdx.x;
    float v = 0.0f;
    if (t < 45) v = 0.1f * ent[t];
    else if (t < 48) v = 6.0f * attr[t - 45];
    for (int d = 1; d < 64; d <<= 1) v += __shfl_xor(v, d);
    if (t == 0) out_loss[0] = v;
}

extern "C" void kernel_launch(void* const* d_in, const int* in_sizes, int n_in,
                              void* d_out, int out_size, void* d_ws, size_t ws_size,
                              hipStream_t stream) {
    const float* fi = (const float*)d_in[0];
    const float* fo = (const float*)d_in[1];
    const float* ft = (const float*)d_in[2];
    const float* ci = (const float*)d_in[3];
    const float* co = (const float*)d_in[4];
    const float* ct = (const float*)d_in[5];
    const float* outin = (const float*)d_in[6];
    float* dout = (float*)d_out;
    char* ws = (char*)d_ws;

    unsigned short* cnorm = (unsigned short*)(ws + 0);        // 98304 B
    float* avg   = (float*)(ws + 98304);                      // 196608 B (dead after K3)
    int* assign  = (int*)(ws + 294912);                       // 196608 B
    float* invd  = (float*)(ws + 491520);                     // 65536 B
    float* attr  = (float*)(ws + 557056);                     // pad 256
    float* ent   = (float*)(ws + 557312);                     // pad 256
    float* partials = (float*)(ws + 557568);                  // 256 * 45000 B = 11.52 MB
    float* sums  = (float*)(ws + 98304);                      // reuse avg region: 180000 B <= 196608 B

    hipLaunchKernelGGL(k1_centnorm, dim3(48), dim3(256), 0, stream, ci, co, ct, cnorm);
    hipLaunchKernelGGL(k2_sim, dim3(768), dim3(256), 0, stream, fi, fo, ft, cnorm, avg, assign);
    hipLaunchKernelGGL(k3_select, dim3(3), dim3(1024), 0, stream, avg, attr);
    hipLaunchKernelGGL(k4_softprep, dim3(4096), dim3(256), 0, stream, outin, dout, invd);
    hipLaunchKernelGGL(k5_seg, dim3(64, 4), dim3(1024), 0, stream, outin, invd, assign, partials);
    hipLaunchKernelGGL(k6a_reduce, dim3(176), dim3(256), 0, stream, partials, sums);
    hipLaunchKernelGGL(k6b_entropy, dim3(45), dim3(256), 0, stream, assign, sums, ent);
    hipLaunchKernelGGL(k7_final, dim3(1), dim3(64), 0, stream, attr, ent, dout + 16384000);
}

// Round 3
// 433.890 us; speedup vs baseline: 1.3269x; 1.3269x over previous
//
#include <hip/hip_runtime.h>
#include <hip/hip_bf16.h>
#include <math.h>

#define B_ROWS 16384
#define DIM    1024
#define CLS    1000
#define KC     15

typedef __attribute__((ext_vector_type(8))) short short8;
typedef __attribute__((ext_vector_type(4))) float f32x4;

__device__ __forceinline__ unsigned short bf16rtn(float x) {
    unsigned u = __float_as_uint(x);
    unsigned r = (u + 0x7FFFu + ((u >> 16) & 1u)) >> 16;
    return (unsigned short)r;
}

// ---------------- K1: centroid normalize -> bf16, [3][16][1024], row 15 zeroed ----------------
__global__ __launch_bounds__(256) void k1_centnorm(const float* c0, const float* c1, const float* c2,
                                                   unsigned short* cnorm) {
    int bx = blockIdx.x;            // 0..47
    int m = bx >> 4, k = bx & 15;
    int t = threadIdx.x;
    unsigned short* outp = cnorm + ((m * 16 + k) << 10);
    if (k == 15) {
        outp[t * 4 + 0] = 0; outp[t * 4 + 1] = 0; outp[t * 4 + 2] = 0; outp[t * 4 + 3] = 0;
        return;
    }
    const float* src = (m == 0 ? c0 : (m == 1 ? c1 : c2)) + (k << 10);
    float4 f = ((const float4*)src)[t];
    float s = f.x * f.x + f.y * f.y + f.z * f.z + f.w * f.w;
    for (int d = 1; d < 64; d <<= 1) s += __shfl_xor(s, d);
    __shared__ float r4[4];
    int w = t >> 6, lane = t & 63;
    if (lane == 0) r4[w] = s;
    __syncthreads();
    float tot = r4[0] + r4[1] + r4[2] + r4[3];
    float inv = 1.0f / fmaxf(sqrtf(tot), 1e-12f);
    outp[t * 4 + 0] = bf16rtn(f.x * inv);
    outp[t * 4 + 1] = bf16rtn(f.y * inv);
    outp[t * 4 + 2] = bf16rtn(f.z * inv);
    outp[t * 4 + 3] = bf16rtn(f.w * inv);
}

// ---------------- K2: sims via MFMA; one 16-row tile per wave ----------------
__global__ __launch_bounds__(256) void k2_sim(const float* f0, const float* f1, const float* f2,
                                              const unsigned short* cnorm, float* avg, int* assign) {
    int t = threadIdx.x;
    int lane = t & 63, w = t >> 6;
    int wg = blockIdx.x * 4 + w;        // 0..3071
    int m = wg >> 10;
    int tile = wg & 1023;
    int row_base = tile << 4;
    const float* fea = (m == 0 ? f0 : (m == 1 ? f1 : f2));

    int nrow = lane & 15;
    int k8 = (lane >> 4) << 3;
    const float* aptr = fea + (size_t)(row_base + nrow) * DIM + k8;
    const short8* bptr = (const short8*)(cnorm + ((m * 16 + nrow) << 10) + k8);

    f32x4 acc = {0.0f, 0.0f, 0.0f, 0.0f};
    float nacc = 0.0f;

#pragma unroll 8
    for (int s = 0; s < 32; ++s) {
        float4 a0 = *(const float4*)(aptr + s * 32);
        float4 a1 = *(const float4*)(aptr + s * 32 + 4);
        short8 bfr = bptr[s * 4];
        short8 afr;
        afr[0] = (short)bf16rtn(a0.x); afr[1] = (short)bf16rtn(a0.y);
        afr[2] = (short)bf16rtn(a0.z); afr[3] = (short)bf16rtn(a0.w);
        afr[4] = (short)bf16rtn(a1.x); afr[5] = (short)bf16rtn(a1.y);
        afr[6] = (short)bf16rtn(a1.z); afr[7] = (short)bf16rtn(a1.w);
        nacc = fmaf(a0.x, a0.x, nacc);
        nacc = fmaf(a0.y, a0.y, nacc);
        nacc = fmaf(a0.z, a0.z, nacc);
        nacc = fmaf(a0.w, a0.w, nacc);
        nacc = fmaf(a1.x, a1.x, nacc);
        nacc = fmaf(a1.y, a1.y, nacc);
        nacc = fmaf(a1.z, a1.z, nacc);
        nacc = fmaf(a1.w, a1.w, nacc);
        acc = __builtin_amdgcn_mfma_f32_16x16x32_bf16(afr, bfr, acc, 0, 0, 0);
    }

    float nsq = nacc;
    nsq += __shfl_xor(nsq, 16);
    nsq += __shfl_xor(nsq, 32);
    float inv = 1.0f / fmaxf(sqrtf(nsq), 1e-12f);

    int c = lane & 15;
    int quad = lane >> 4;
#pragma unroll
    for (int j = 0; j < 4; ++j) {
        int r = quad * 4 + j;
        float invr = __shfl(inv, r);
        float simv = acc[j] * invr;
        float sv = (c < 15) ? simv : 0.0f;
        float mv = (c < 15) ? simv : -INFINITY;
        int mi = c;
        for (int s = 1; s <= 8; s <<= 1) {
            sv += __shfl_xor(sv, s);
            float ov = __shfl_xor(mv, s);
            int oi = __shfl_xor(mi, s);
            bool take = (ov > mv) || (ov == mv && oi < mi);
            mv = take ? ov : mv;
            mi = take ? oi : mi;
        }
        if (c == 0) {
            int row = row_base + r;
            avg[m * B_ROWS + row] = sv * (1.0f / 15.0f);
            assign[m * B_ROWS + row] = mi;
        }
    }
}

// ---------------- K3: exact kth-smallest (rank 6554, 0-based) + attractive loss ----------------
__global__ __launch_bounds__(1024) void k3_select(const float* avg, float* attr_out) {
    int m = blockIdx.x;
    int t = threadIdx.x;
    const float* a = avg + m * B_ROWS;
    float av[16];
    unsigned kv[16];
#pragma unroll
    for (int i = 0; i < 16; ++i) {
        float x = a[i * 1024 + t];
        av[i] = x;
        unsigned u = __float_as_uint(x);
        kv[i] = (u & 0x80000000u) ? ~u : (u | 0x80000000u);
    }
    __shared__ unsigned sP, sR;
    __shared__ int ri[16];
    __shared__ float rf[16];
    if (t == 0) { sP = 0u; sR = 6554u; }
    __syncthreads();
    int w = t >> 6, lane = t & 63;
    for (int bit = 31; bit >= 0; --bit) {
        unsigned pref = sP;
        unsigned rr = sR;
        unsigned maskH = (bit == 31) ? 0u : (0xFFFFFFFFu << (bit + 1));
        int cnt = 0;
#pragma unroll
        for (int i = 0; i < 16; ++i) {
            bool match = (((kv[i] ^ pref) & maskH) == 0u);
            bool zero = (((kv[i] >> bit) & 1u) == 0u);
            cnt += (match && zero) ? 1 : 0;
        }
        for (int d = 1; d < 64; d <<= 1) cnt += __shfl_xor(cnt, d);
        if (lane == 0) ri[w] = cnt;
        __syncthreads();
        if (t == 0) {
            int c0 = 0;
            for (int i = 0; i < 16; ++i) c0 += ri[i];
            if ((int)rr >= c0) { sP = pref | (1u << bit); sR = rr - (unsigned)c0; }
        }
        __syncthreads();
    }
    unsigned key = sP;
    float thr = (key & 0x80000000u) ? __uint_as_float(key & 0x7FFFFFFFu)
                                    : __uint_as_float(~key);
    float s = 0.0f;
#pragma unroll
    for (int i = 0; i < 16; ++i) {
        float x = av[i];
        float wgt = 1.0f / (1.0f + __expf(-5.0f * (x - thr)));
        s += wgt * (1.0f - x);
    }
    for (int d = 1; d < 64; d <<= 1) s += __shfl_xor(s, d);
    if (lane == 0) rf[w] = s;
    __syncthreads();
    if (t == 0) {
        float tot = 0.0f;
        for (int i = 0; i < 16; ++i) tot += rf[i];
        attr_out[m] = tot / 16384.0f;
    }
}

// ---------------- K4: per-row sumexp + exact out copy ----------------
__global__ __launch_bounds__(256) void k4_softprep(const float* out_in, float* out_copy, float* inv_denom) {
    int w = threadIdx.x >> 6, lane = threadIdx.x & 63;
    int row = blockIdx.x * 4 + w;
    const float4* src = (const float4*)(out_in + (size_t)row * CLS);
    float4* dst = (float4*)(out_copy + (size_t)row * CLS);
    float s = 0.0f;
#pragma unroll
    for (int i = 0; i < 4; ++i) {
        int idx = i * 64 + lane;
        if (idx < 250) {
            float4 v = src[idx];
            dst[idx] = v;
            s += __expf(v.x) + __expf(v.y) + __expf(v.z) + __expf(v.w);
        }
    }
    for (int d = 1; d < 64; d <<= 1) s += __shfl_xor(s, d);
    if (lane == 0) inv_denom[row] = 1.0f / s;
}

// ---------------- K5: single-owner LDS accumulation (no atomics, no register switch) ----------------
// Block = 256 threads = ONE column slot (cl = t). red[3][KC][256] = 46080 B is
// block-private, and cell [*][*][cl] is touched ONLY by thread cl: all 4 waves
// process the same row each iteration, so the segmented accumulate is a plain
// ds_read + v_add + ds_write per modality. No sync in the loop, no atomic pipe.
// 2-deep software pipeline hides the global-load latency (12 waves/CU at 3 blk/CU).
__global__ __launch_bounds__(256) void k5_seg(const float* out_in, const float* inv_denom,
                                              const int* assign, float* partials, int nblk) {
    int t = threadIdx.x;                // cl
    int q = blockIdx.y;                 // column quarter
    bool active = (t < 250);
    int colbase = q * 250 + t;

    __shared__ float red[3 * KC * 256];
    // thread t zeroes exactly the cells it owns (i % 256 == t): no barrier needed
    for (int i = t; i < 3 * KC * 256; i += 256) red[i] = 0.0f;

    int stride = nblk;
    int row = blockIdx.x;

    // prologue: prefetch first row
    float x = 0.0f;
    if (active) x = out_in[(size_t)row * CLS + colbase];
    float idv = inv_denom[row];
    int a0 = assign[row];
    int a1 = assign[B_ROWS + row];
    int a2 = assign[2 * B_ROWS + row];

    while (true) {
        int nrow = row + stride;
        float xn = 0.0f, idn = 0.0f;
        int b0 = 0, b1 = 0, b2 = 0;
        bool more = (nrow < B_ROWS);
        if (more) {
            if (active) xn = out_in[(size_t)nrow * CLS + colbase];
            idn = inv_denom[nrow];
            b0 = assign[nrow];
            b1 = assign[B_ROWS + nrow];
            b2 = assign[2 * B_ROWS + nrow];
        }
        if (active) {
            float p = __expf(x) * idv;
            red[a0 * 256 + t] += p;
            red[(KC + a1) * 256 + t] += p;
            red[(2 * KC + a2) * 256 + t] += p;
        }
        if (!more) break;
        row = nrow; x = xn; idv = idn; a0 = b0; a1 = b1; a2 = b2;
    }
    __syncthreads();

    float* dst = partials + (size_t)(blockIdx.y * nblk + blockIdx.x) * (3 * KC * 250);
    for (int i = t; i < 3 * KC * 250; i += 256) {
        dst[i] = red[(i / 250) * 256 + (i % 250)];
    }
}

// ---------------- K6a: fully-parallel reduce of partials over the nblk row-chunks ----------------
// sums[q][m][k][cl], ascending-b order.
__global__ __launch_bounds__(256) void k6a_reduce(const float* partials, float* sums, int nblk) {
    int i = blockIdx.x * 256 + threadIdx.x;     // 0..44999
    if (i >= 4 * 3 * KC * 250) return;
    int q = i / (3 * KC * 250);
    int j = i - q * (3 * KC * 250);
    const float* p = partials + (size_t)q * nblk * (3 * KC * 250) + j;
    float s = 0.0f;
    for (int b = 0; b < nblk; ++b)
        s += p[(size_t)b * (3 * KC * 250)];
    sums[i] = s;
}

// ---------------- K6b: per-(m,k) entropy from sums, gated on count>=3 ----------------
__global__ __launch_bounds__(256) void k6b_entropy(const int* assign, const float* sums,
                                                   float* ent_out) {
    int bx = blockIdx.x;        // 0..44
    int m = bx / KC, k = bx % KC;
    int t = threadIdx.x;
    int w = t >> 6, lane = t & 63;
    int cnt = 0;
    for (int e = t; e < B_ROWS; e += 256) cnt += (assign[m * B_ROWS + e] == k) ? 1 : 0;
    for (int d = 1; d < 64; d <<= 1) cnt += __shfl_xor(cnt, d);
    __shared__ int ri[4];
    __shared__ float rf[4];
    if (lane == 0) ri[w] = cnt;
    __syncthreads();
    int count = ri[0] + ri[1] + ri[2] + ri[3];
    float denom = fmaxf((float)count, 1.0f);
    float es = 0.0f;
    for (int c = t; c < CLS; c += 256) {
        int q = c / 250, cl = c % 250;
        float s = sums[q * (3 * KC * 250) + (m * KC + k) * 250 + cl];
        float mp = s / denom;
        es += mp * __logf(mp + 1e-8f);
    }
    for (int d = 1; d < 64; d <<= 1) es += __shfl_xor(es, d);
    if (lane == 0) rf[w] = es;
    __syncthreads();
    if (t == 0) {
        float ent = rf[0] + rf[1] + rf[2] + rf[3];
        ent_out[m * KC + k] = (count >= 3) ? ent : 0.0f;
    }
}

// ---------------- K7: final scalar ----------------
__global__ __launch_bounds__(64) void k7_final(const float* attr, const float* ent, float* out_loss) {
    int t = threadIdx.x;
    float v = 0.0f;
    if (t < 45) v = 0.1f * ent[t];
    else if (t < 48) v = 6.0f * attr[t - 45];
    for (int d = 1; d < 64; d <<= 1) v += __shfl_xor(v, d);
    if (t == 0) out_loss[0] = v;
}

extern "C" void kernel_launch(void* const* d_in, const int* in_sizes, int n_in,
                              void* d_out, int out_size, void* d_ws, size_t ws_size,
                              hipStream_t stream) {
    const float* fi = (const float*)d_in[0];
    const float* fo = (const float*)d_in[1];
    const float* ft = (const float*)d_in[2];
    const float* ci = (const float*)d_in[3];
    const float* co = (const float*)d_in[4];
    const float* ct = (const float*)d_in[5];
    const float* outin = (const float*)d_in[6];
    float* dout = (float*)d_out;
    char* ws = (char*)d_ws;

    unsigned short* cnorm = (unsigned short*)(ws + 0);        // 98304 B
    float* avg   = (float*)(ws + 98304);                      // 196608 B (dead after K3)
    int* assign  = (int*)(ws + 294912);                       // 196608 B
    float* invd  = (float*)(ws + 491520);                     // 65536 B
    float* attr  = (float*)(ws + 557056);                     // pad 256
    float* ent   = (float*)(ws + 557312);                     // pad 256
    float* partials = (float*)(ws + 557568);                  // nblk*4*11250*4 B
    float* sums  = (float*)(ws + 98304);                      // reuse avg region: 180000 B <= 196608 B

    // Choose k5 grid-x from available workspace. Per x-block partials cost:
    // 4 quarters * 11250 floats * 4 B = 180000 B.
    // nblk=192 -> 34.56 MB (3 blk/CU), 128 -> 23.04 MB (2 blk/CU), 64 -> 11.52 MB (proven fit).
    size_t base = 557568;
    int nblk = 64;
    if (ws_size >= base + (size_t)192 * 180000) nblk = 192;
    else if (ws_size >= base + (size_t)128 * 180000) nblk = 128;

    hipLaunchKernelGGL(k1_centnorm, dim3(48), dim3(256), 0, stream, ci, co, ct, cnorm);
    hipLaunchKernelGGL(k2_sim, dim3(768), dim3(256), 0, stream, fi, fo, ft, cnorm, avg, assign);
    hipLaunchKernelGGL(k3_select, dim3(3), dim3(1024), 0, stream, avg, attr);
    hipLaunchKernelGGL(k4_softprep, dim3(4096), dim3(256), 0, stream, outin, dout, invd);
    hipLaunchKernelGGL(k5_seg, dim3(nblk, 4), dim3(256), 0, stream, outin, invd, assign, partials, nblk);
    hipLaunchKernelGGL(k6a_reduce, dim3(176), dim3(256), 0, stream, partials, sums, nblk);
    hipLaunchKernelGGL(k6b_entropy, dim3(45), dim3(256), 0, stream, assign, sums, ent);
    hipLaunchKernelGGL(k7_final, dim3(1), dim3(64), 0, stream, attr, ent, dout + 16384000);
}

// Round 6
// 422.536 us; speedup vs baseline: 1.3625x; 1.0269x over previous
//
#include <hip/hip_runtime.h>
#include <hip/hip_bf16.h>
#include <math.h>

#define B_ROWS 16384
#define DIM    1024
#define CLS    1000
#define KC     15

typedef __attribute__((ext_vector_type(8))) short short8;
typedef __attribute__((ext_vector_type(4))) float f32x4;

__device__ __forceinline__ unsigned short bf16rtn(float x) {
    unsigned u = __float_as_uint(x);
    unsigned r = (u + 0x7FFFu + ((u >> 16) & 1u)) >> 16;
    return (unsigned short)r;
}

// ---------------- K1: centroid normalize -> bf16, [3][16][1024], row 15 zeroed ----------------
__global__ __launch_bounds__(256) void k1_centnorm(const float* c0, const float* c1, const float* c2,
                                                   unsigned short* cnorm) {
    int bx = blockIdx.x;            // 0..47
    int m = bx >> 4, k = bx & 15;
    int t = threadIdx.x;
    unsigned short* outp = cnorm + ((m * 16 + k) << 10);
    if (k == 15) {
        outp[t * 4 + 0] = 0; outp[t * 4 + 1] = 0; outp[t * 4 + 2] = 0; outp[t * 4 + 3] = 0;
        return;
    }
    const float* src = (m == 0 ? c0 : (m == 1 ? c1 : c2)) + (k << 10);
    float4 f = ((const float4*)src)[t];
    float s = f.x * f.x + f.y * f.y + f.z * f.z + f.w * f.w;
    for (int d = 1; d < 64; d <<= 1) s += __shfl_xor(s, d);
    __shared__ float r4[4];
    int w = t >> 6, lane = t & 63;
    if (lane == 0) r4[w] = s;
    __syncthreads();
    float tot = r4[0] + r4[1] + r4[2] + r4[3];
    float inv = 1.0f / fmaxf(sqrtf(tot), 1e-12f);
    outp[t * 4 + 0] = bf16rtn(f.x * inv);
    outp[t * 4 + 1] = bf16rtn(f.y * inv);
    outp[t * 4 + 2] = bf16rtn(f.z * inv);
    outp[t * 4 + 3] = bf16rtn(f.w * inv);
}

// ---------------- K2: sims via MFMA; one 16-row tile per BLOCK, K split across 4 waves ----------------
// Round-3 evidence: 92 us, VALUBusy 6%, Occupancy 31% -> latency-bound at 12 waves/CU
// (grid-limited). K-split gives 12288 waves (32/CU cap) with a 5 KB LDS combine.
__global__ __launch_bounds__(256) void k2_sim(const float* f0, const float* f1, const float* f2,
                                              const unsigned short* cnorm, float* avg, int* assign) {
    int t = threadIdx.x;
    int lane = t & 63, w = t >> 6;          // wave w owns K-range [w*256, w*256+256)
    int bx = blockIdx.x;                    // 0..3071
    int m = bx >> 10;
    int tile = bx & 1023;
    int row_base = tile << 4;
    const float* fea = (m == 0 ? f0 : (m == 1 ? f1 : f2));

    int nrow = lane & 15;
    int k8 = (lane >> 4) << 3;
    int kofs = w * 256 + k8;
    const float* aptr = fea + (size_t)(row_base + nrow) * DIM + kofs;
    const short8* bptr = (const short8*)(cnorm + ((m * 16 + nrow) << 10) + kofs);

    f32x4 acc = {0.0f, 0.0f, 0.0f, 0.0f};
    float nacc = 0.0f;

#pragma unroll
    for (int s = 0; s < 8; ++s) {
        float4 a0 = *(const float4*)(aptr + s * 32);
        float4 a1 = *(const float4*)(aptr + s * 32 + 4);
        short8 bfr = bptr[s * 4];
        short8 afr;
        afr[0] = (short)bf16rtn(a0.x); afr[1] = (short)bf16rtn(a0.y);
        afr[2] = (short)bf16rtn(a0.z); afr[3] = (short)bf16rtn(a0.w);
        afr[4] = (short)bf16rtn(a1.x); afr[5] = (short)bf16rtn(a1.y);
        afr[6] = (short)bf16rtn(a1.z); afr[7] = (short)bf16rtn(a1.w);
        nacc = fmaf(a0.x, a0.x, nacc);
        nacc = fmaf(a0.y, a0.y, nacc);
        nacc = fmaf(a0.z, a0.z, nacc);
        nacc = fmaf(a0.w, a0.w, nacc);
        nacc = fmaf(a1.x, a1.x, nacc);
        nacc = fmaf(a1.y, a1.y, nacc);
        nacc = fmaf(a1.z, a1.z, nacc);
        nacc = fmaf(a1.w, a1.w, nacc);
        acc = __builtin_amdgcn_mfma_f32_16x16x32_bf16(afr, bfr, acc, 0, 0, 0);
    }

    // cross-wave combine: partial C-fragments and partial row-norms
    __shared__ f32x4 sacc[4][64];           // 4 KB
    __shared__ float snrm[4][64];           // 1 KB
    sacc[w][lane] = acc;
    snrm[w][lane] = nacc;
    __syncthreads();
    if (w != 0) return;

    f32x4 a = sacc[0][lane] + sacc[1][lane] + sacc[2][lane] + sacc[3][lane];
    float nsq = snrm[0][lane] + snrm[1][lane] + snrm[2][lane] + snrm[3][lane];
    nsq += __shfl_xor(nsq, 16);
    nsq += __shfl_xor(nsq, 32);
    float inv = 1.0f / fmaxf(sqrtf(nsq), 1e-12f);

    int c = lane & 15;
    int quad = lane >> 4;
#pragma unroll
    for (int j = 0; j < 4; ++j) {
        int r = quad * 4 + j;
        float invr = __shfl(inv, r);
        float simv = a[j] * invr;
        float sv = (c < 15) ? simv : 0.0f;
        float mv = (c < 15) ? simv : -INFINITY;
        int mi = c;
        for (int s = 1; s <= 8; s <<= 1) {
            sv += __shfl_xor(sv, s);
            float ov = __shfl_xor(mv, s);
            int oi = __shfl_xor(mi, s);
            bool take = (ov > mv) || (ov == mv && oi < mi);
            mv = take ? ov : mv;
            mi = take ? oi : mi;
        }
        if (c == 0) {
            int row = row_base + r;
            avg[m * B_ROWS + row] = sv * (1.0f / 15.0f);
            assign[m * B_ROWS + row] = mi;
        }
    }
}

// ---------------- K3: exact kth-smallest (rank 6554, 0-based) + attractive loss ----------------
__global__ __launch_bounds__(1024) void k3_select(const float* avg, float* attr_out) {
    int m = blockIdx.x;
    int t = threadIdx.x;
    const float* a = avg + m * B_ROWS;
    float av[16];
    unsigned kv[16];
#pragma unroll
    for (int i = 0; i < 16; ++i) {
        float x = a[i * 1024 + t];
        av[i] = x;
        unsigned u = __float_as_uint(x);
        kv[i] = (u & 0x80000000u) ? ~u : (u | 0x80000000u);
    }
    __shared__ unsigned sP, sR;
    __shared__ int ri[16];
    __shared__ float rf[16];
    if (t == 0) { sP = 0u; sR = 6554u; }
    __syncthreads();
    int w = t >> 6, lane = t & 63;
    for (int bit = 31; bit >= 0; --bit) {
        unsigned pref = sP;
        unsigned rr = sR;
        unsigned maskH = (bit == 31) ? 0u : (0xFFFFFFFFu << (bit + 1));
        int cnt = 0;
#pragma unroll
        for (int i = 0; i < 16; ++i) {
            bool match = (((kv[i] ^ pref) & maskH) == 0u);
            bool zero = (((kv[i] >> bit) & 1u) == 0u);
            cnt += (match && zero) ? 1 : 0;
        }
        for (int d = 1; d < 64; d <<= 1) cnt += __shfl_xor(cnt, d);
        if (lane == 0) ri[w] = cnt;
        __syncthreads();
        if (t == 0) {
            int c0 = 0;
            for (int i = 0; i < 16; ++i) c0 += ri[i];
            if ((int)rr >= c0) { sP = pref | (1u << bit); sR = rr - (unsigned)c0; }
        }
        __syncthreads();
    }
    unsigned key = sP;
    float thr = (key & 0x80000000u) ? __uint_as_float(key & 0x7FFFFFFFu)
                                    : __uint_as_float(~key);
    float s = 0.0f;
#pragma unroll
    for (int i = 0; i < 16; ++i) {
        float x = av[i];
        float wgt = 1.0f / (1.0f + __expf(-5.0f * (x - thr)));
        s += wgt * (1.0f - x);
    }
    for (int d = 1; d < 64; d <<= 1) s += __shfl_xor(s, d);
    if (lane == 0) rf[w] = s;
    __syncthreads();
    if (t == 0) {
        float tot = 0.0f;
        for (int i = 0; i < 16; ++i) tot += rf[i];
        attr_out[m] = tot / 16384.0f;
    }
}

// ---------------- K4: per-row sumexp + exact out copy ----------------
__global__ __launch_bounds__(256) void k4_softprep(const float* out_in, float* out_copy, float* inv_denom) {
    int w = threadIdx.x >> 6, lane = threadIdx.x & 63;
    int row = blockIdx.x * 4 + w;
    const float4* src = (const float4*)(out_in + (size_t)row * CLS);
    float4* dst = (float4*)(out_copy + (size_t)row * CLS);
    float s = 0.0f;
#pragma unroll
    for (int i = 0; i < 4; ++i) {
        int idx = i * 64 + lane;
        if (idx < 250) {
            float4 v = src[idx];
            dst[idx] = v;
            s += __expf(v.x) + __expf(v.y) + __expf(v.z) + __expf(v.w);
        }
    }
    for (int d = 1; d < 64; d <<= 1) s += __shfl_xor(s, d);
    if (lane == 0) inv_denom[row] = 1.0f / s;
}

// ---------------- K5: single-owner LDS accumulation (no atomics, no register switch) ----------------
__global__ __launch_bounds__(256) void k5_seg(const float* out_in, const float* inv_denom,
                                              const int* assign, float* partials, int nblk) {
    int t = threadIdx.x;                // cl
    int q = blockIdx.y;                 // column quarter
    bool active = (t < 250);
    int colbase = q * 250 + t;

    __shared__ float red[3 * KC * 256];
    for (int i = t; i < 3 * KC * 256; i += 256) red[i] = 0.0f;

    int stride = nblk;
    int row = blockIdx.x;

    float x = 0.0f;
    if (active) x = out_in[(size_t)row * CLS + colbase];
    float idv = inv_denom[row];
    int a0 = assign[row];
    int a1 = assign[B_ROWS + row];
    int a2 = assign[2 * B_ROWS + row];

    while (true) {
        int nrow = row + stride;
        float xn = 0.0f, idn = 0.0f;
        int b0 = 0, b1 = 0, b2 = 0;
        bool more = (nrow < B_ROWS);
        if (more) {
            if (active) xn = out_in[(size_t)nrow * CLS + colbase];
            idn = inv_denom[nrow];
            b0 = assign[nrow];
            b1 = assign[B_ROWS + nrow];
            b2 = assign[2 * B_ROWS + nrow];
        }
        if (active) {
            float p = __expf(x) * idv;
            red[a0 * 256 + t] += p;
            red[(KC + a1) * 256 + t] += p;
            red[(2 * KC + a2) * 256 + t] += p;
        }
        if (!more) break;
        row = nrow; x = xn; idv = idn; a0 = b0; a1 = b1; a2 = b2;
    }
    __syncthreads();

    float* dst = partials + (size_t)(blockIdx.y * nblk + blockIdx.x) * (3 * KC * 250);
    for (int i = t; i < 3 * KC * 250; i += 256) {
        dst[i] = red[(i / 250) * 256 + (i % 250)];
    }
}

// ---------------- K6a: fully-parallel reduce of partials over the nblk row-chunks ----------------
// sums[q][m][k][cl], ascending-b order. (Round-3 proven version.)
__global__ __launch_bounds__(256) void k6a_reduce(const float* partials, float* sums, int nblk) {
    int i = blockIdx.x * 256 + threadIdx.x;     // 0..44999
    if (i >= 4 * 3 * KC * 250) return;
    int q = i / (3 * KC * 250);
    int j = i - q * (3 * KC * 250);
    const float* p = partials + (size_t)q * nblk * (3 * KC * 250) + j;
    float s = 0.0f;
    for (int b = 0; b < nblk; ++b)
        s += p[(size_t)b * (3 * KC * 250)];
    sums[i] = s;
}

// ---------------- K6b: per-(m,k) entropy from sums, gated on count>=3 ----------------
__global__ __launch_bounds__(256) void k6b_entropy(const int* assign, const float* sums,
                                                   float* ent_out) {
    int bx = blockIdx.x;        // 0..44
    int m = bx / KC, k = bx % KC;
    int t = threadIdx.x;
    int w = t >> 6, lane = t & 63;
    int cnt = 0;
    for (int e = t; e < B_ROWS; e += 256) cnt += (assign[m * B_ROWS + e] == k) ? 1 : 0;
    for (int d = 1; d < 64; d <<= 1) cnt += __shfl_xor(cnt, d);
    __shared__ int ri[4];
    __shared__ float rf[4];
    if (lane == 0) ri[w] = cnt;
    __syncthreads();
    int count = ri[0] + ri[1] + ri[2] + ri[3];
    float denom = fmaxf((float)count, 1.0f);
    float es = 0.0f;
    for (int c = t; c < CLS; c += 256) {
        int q = c / 250, cl = c % 250;
        float s = sums[q * (3 * KC * 250) + (m * KC + k) * 250 + cl];
        float mp = s / denom;
        es += mp * __logf(mp + 1e-8f);
    }
    for (int d = 1; d < 64; d <<= 1) es += __shfl_xor(es, d);
    if (lane == 0) rf[w] = es;
    __syncthreads();
    if (t == 0) {
        float ent = rf[0] + rf[1] + rf[2] + rf[3];
        ent_out[m * KC + k] = (count >= 3) ? ent : 0.0f;
    }
}

// ---------------- K7: final scalar ----------------
__global__ __launch_bounds__(64) void k7_final(const float* attr, const float* ent, float* out_loss) {
    int t = threadIdx.x;
    float v = 0.0f;
    if (t < 45) v = 0.1f * ent[t];
    else if (t < 48) v = 6.0f * attr[t - 45];
    for (int d = 1; d < 64; d <<= 1) v += __shfl_xor(v, d);
    if (t == 0) out_loss[0] = v;
}

extern "C" void kernel_launch(void* const* d_in, const int* in_sizes, int n_in,
                              void* d_out, int out_size, void* d_ws, size_t ws_size,
                              hipStream_t stream) {
    const float* fi = (const float*)d_in[0];
    const float* fo = (const float*)d_in[1];
    const float* ft = (const float*)d_in[2];
    const float* ci = (const float*)d_in[3];
    const float* co = (const float*)d_in[4];
    const float* ct = (const float*)d_in[5];
    const float* outin = (const float*)d_in[6];
    float* dout = (float*)d_out;
    char* ws = (char*)d_ws;

    unsigned short* cnorm = (unsigned short*)(ws + 0);        // 98304 B
    float* avg   = (float*)(ws + 98304);                      // 196608 B (dead after K3)
    int* assign  = (int*)(ws + 294912);                       // 196608 B
    float* invd  = (float*)(ws + 491520);                     // 65536 B
    float* attr  = (float*)(ws + 557056);                     // pad 256
    float* ent   = (float*)(ws + 557312);                     // pad 256
    float* partials = (float*)(ws + 557568);                  // nblk*4*11250*4 B
    float* sums  = (float*)(ws + 98304);                      // reuse avg region: 180000 B <= 196608 B

    size_t base = 557568;
    int nblk = 64;
    if (ws_size >= base + (size_t)192 * 180000) nblk = 192;
    else if (ws_size >= base + (size_t)128 * 180000) nblk = 128;

    hipLaunchKernelGGL(k1_centnorm, dim3(48), dim3(256), 0, stream, ci, co, ct, cnorm);
    hipLaunchKernelGGL(k2_sim, dim3(3072), dim3(256), 0, stream, fi, fo, ft, cnorm, avg, assign);
    hipLaunchKernelGGL(k3_select, dim3(3), dim3(1024), 0, stream, avg, attr);
    hipLaunchKernelGGL(k4_softprep, dim3(4096), dim3(256), 0, stream, outin, dout, invd);
    hipLaunchKernelGGL(k5_seg, dim3(nblk, 4), dim3(256), 0, stream, outin, invd, assign, partials, nblk);
    hipLaunchKernelGGL(k6a_reduce, dim3(176), dim3(256), 0, stream, partials, sums, nblk);
    hipLaunchKernelGGL(k6b_entropy, dim3(45), dim3(256), 0, stream, assign, sums, ent);
    hipLaunchKernelGGL(k7_final, dim3(1), dim3(64), 0, stream, attr, ent, dout + 16384000);
}